// Round 5
// baseline (174.279 us; speedup 1.0000x reference)
//
#include <hip/hip_runtime.h>

// Problem: B=64, H=W=512 fp32. out = x + (f - conv3x3(x,k_b)) / 6, zero pad,
// cross-correlation (no kernel flip).
//
// R5 = R4 + two changes attacking the 2.9 TB/s plateau:
//  1. XCD swizzle: hardware round-robins blockIdx across 8 XCDs; we remap so
//     XCD x gets a CONTIGUOUS logical range (8 images). Overlapping stencil
//     rows are then reused inside one XCD's 4 MiB L2 instead of bouncing
//     through L3/fabric.
//  2. Vertical 2-row pairing: each thread loads 4 x-rows and computes 2
//     output rows (shared middle rows) -> x read 1.5x per output instead of
//     3x, and 6 KB of independent loads in flight per wave. Stores remain
//     contiguous wave-wide 1 KB lines (the R3 write-amplification trap is
//     avoided).
#define BB 64
#define HH 512
#define WW 512
#define W4 (WW / 4)

struct RowE { float4 v; float l, r; };  // quad + left/right halo floats

__device__ __forceinline__ RowE load_row(const float* __restrict__ xrow,
                                         int j0, int lane) {
    RowE r;
    r.v = *(const float4*)(xrow + j0);
    float lh = __shfl_up(r.v.w, 1);
    float rh = __shfl_down(r.v.x, 1);
    if (lane == 0)  lh = (j0 > 0)      ? xrow[j0 - 1] : 0.f;
    if (lane == 63) rh = (j0 + 4 < WW) ? xrow[j0 + 4] : 0.f;
    r.l = lh; r.r = rh;
    return r;
}

__device__ __forceinline__ RowE zero_row() {
    RowE r;
    r.v = make_float4(0.f, 0.f, 0.f, 0.f);
    r.l = 0.f; r.r = 0.f;
    return r;
}

// stencil for one output row given window rows (t)op,(c)enter,(b)ottom
__device__ __forceinline__ float4 stencil(
    const RowE& t, const RowE& c, const RowE& bo,
    float k00, float k01, float k02,
    float k10, float k11, float k12,
    float k20, float k21, float k22)
{
    float4 acc;
    acc.x = k00 * t.l   + k01 * t.v.x + k02 * t.v.y
          + k10 * c.l   + k11 * c.v.x + k12 * c.v.y
          + k20 * bo.l  + k21 * bo.v.x + k22 * bo.v.y;
    acc.y = k00 * t.v.x + k01 * t.v.y + k02 * t.v.z
          + k10 * c.v.x + k11 * c.v.y + k12 * c.v.z
          + k20 * bo.v.x + k21 * bo.v.y + k22 * bo.v.z;
    acc.z = k00 * t.v.y + k01 * t.v.z + k02 * t.v.w
          + k10 * c.v.y + k11 * c.v.z + k12 * c.v.w
          + k20 * bo.v.y + k21 * bo.v.z + k22 * bo.v.w;
    acc.w = k00 * t.v.z + k01 * t.v.w + k02 * t.r
          + k10 * c.v.z + k11 * c.v.w + k12 * c.r
          + k20 * bo.v.z + k21 * bo.v.w + k22 * bo.r;
    return acc;
}

__global__ __launch_bounds__(256) void jacobi_v5_kernel(
    const float* __restrict__ x,
    const float* __restrict__ f,
    const float* __restrict__ k,
    float* __restrict__ out)
{
    const int tid  = threadIdx.x;
    const int lane = tid & 63;

    // XCD swizzle: 8192 blocks; XCD (n&7) gets logical range [ (n&7)*1024, +1024 )
    const int nb      = blockIdx.x;
    const int logical = (nb & 7) * 1024 + (nb >> 3);

    const int b   = logical >> 7;        // image (128 blocks per image)
    const int blk = logical & 127;       // 4-row group within image
    const int r0  = blk << 2;

    const int half = tid >> 7;           // 0: rows r0,r0+1  1: rows r0+2,r0+3
    const int j4   = tid & 127;
    const int j0   = j4 << 2;
    const int r    = r0 + (half << 1);   // first output row of this thread

    const size_t img = (size_t)b * HH * WW;
    const float* xb = x + img;

    const float* kb = k + b * 9;  // b scalar -> s_load
    const float k00 = kb[0], k01 = kb[1], k02 = kb[2];
    const float k10 = kb[3], k11 = kb[4], k12 = kb[5];
    const float k20 = kb[6], k21 = kb[7], k22 = kb[8];

    // 4 stencil rows: r-1, r, r+1, r+2 (edge branches are wave-uniform)
    const RowE ra = (r > 0)      ? load_row(xb + (size_t)(r - 1) * WW, j0, lane)
                                 : zero_row();
    const RowE rb = load_row(xb + (size_t)r * WW, j0, lane);
    const RowE rc = load_row(xb + (size_t)(r + 1) * WW, j0, lane);
    const RowE rd = (r + 2 < HH) ? load_row(xb + (size_t)(r + 2) * WW, j0, lane)
                                 : zero_row();

    const size_t idx0 = (size_t)b * HH * W4 + (size_t)r * W4 + j4;
    const float4 f0 = ((const float4*)f)[idx0];
    const float4 f1 = ((const float4*)f)[idx0 + W4];

    const float4 a0 = stencil(ra, rb, rc, k00,k01,k02, k10,k11,k12, k20,k21,k22);
    const float4 a1 = stencil(rb, rc, rd, k00,k01,k02, k10,k11,k12, k20,k21,k22);

    const float inv6 = 1.f / 6.f;
    float4 o0, o1;
    o0.x = rb.v.x + (f0.x - a0.x) * inv6;
    o0.y = rb.v.y + (f0.y - a0.y) * inv6;
    o0.z = rb.v.z + (f0.z - a0.z) * inv6;
    o0.w = rb.v.w + (f0.w - a0.w) * inv6;
    o1.x = rc.v.x + (f1.x - a1.x) * inv6;
    o1.y = rc.v.y + (f1.y - a1.y) * inv6;
    o1.z = rc.v.z + (f1.z - a1.z) * inv6;
    o1.w = rc.v.w + (f1.w - a1.w) * inv6;

    ((float4*)out)[idx0]      = o0;
    ((float4*)out)[idx0 + W4] = o1;
}

extern "C" void kernel_launch(void* const* d_in, const int* in_sizes, int n_in,
                              void* d_out, int out_size, void* d_ws, size_t ws_size,
                              hipStream_t stream) {
    const float* x  = (const float*)d_in[0];
    const float* f  = (const float*)d_in[1];
    const float* kk = (const float*)d_in[2];
    float* out = (float*)d_out;

    // 64 images * 128 four-row groups = 8192 blocks of 256 threads.
    const int blocks = BB * (HH / 4);
    jacobi_v5_kernel<<<blocks, 256, 0, stream>>>(x, f, kk, out);
}